// Round 8
// baseline (29893.433 us; speedup 1.0000x reference)
//
#include <hip/hip_runtime.h>
#include <math.h>

// ============================================================================
// AR_Transcriber round 13.
// r12 (inline proj) REGRESSED (17.0->21.5ms steady): proj dot+prev RV went
// serial inside every step. REVERT to r11 structure (best: 17.0 steady).
// New lever: r10 proved coherent-path transactions are the dominant cost.
// r11 moved ~23MB/step on the sc0sc1 LLC path (each of 236 blocks gathers
// the FULL 768-dim state). This round halves participants: 96 compute
// blocks x 512 threads (8 dims each) + 22 proj blocks x 512 threads
// (20 rows each) => ~11.5MB/step coherent traffic, 96/22 flag fan-in.
// Cell = 2 dims/thread in wave 0, preserving r11's shfl-publish idiom.
// All r11 rendezvous/overlap scheduling retained.
// ============================================================================

typedef unsigned long long ull;

#define ACO_FL 6266880ull  // 510*16*768
#define F1_OFF 0           // 96 flags * 16 u32 stride
#define F2_OFF 1536
#define FP_OFF 3072        // 22 proj flags * 16 u32 stride
#define BAR_U32 4096
#define NCOMP 96
#define NPROJ 22

__device__ __forceinline__ float sigf(float x) { return 1.0f / (1.0f + expf(-x)); }

__device__ __forceinline__ ull pack2(float x, float y) {
  union { float f[2]; ull u; } c; c.f[0] = x; c.f[1] = y; return c.u;
}
__device__ __forceinline__ ull at_load(const ull* p) {
  return __hip_atomic_load((ull*)p, __ATOMIC_RELAXED, __HIP_MEMORY_SCOPE_AGENT);
}
__device__ __forceinline__ void at_store(ull* p, ull v) {
  __hip_atomic_store(p, v, __ATOMIC_RELAXED, __HIP_MEMORY_SCOPE_AGENT);
}

// Device-coherent (sc0|sc1 = 17) global -> LDS direct copy, 16B/lane.
__device__ __forceinline__ void gl2lds(const float4* g, float* l) {
  __builtin_amdgcn_global_load_lds(
      (const __attribute__((address_space(1))) void*)(g),
      (__attribute__((address_space(3))) void*)(l), 16, 0, 17);
}
// Cached variant (input written by a prior dispatch).
__device__ __forceinline__ void gl2lds_nc(const float4* g, float* l) {
  __builtin_amdgcn_global_load_lds(
      (const __attribute__((address_space(1))) void*)(g),
      (__attribute__((address_space(3))) void*)(l), 16, 0, 0);
}

// Parallel per-producer flag wait with backoff: thread tid<n polls line tid.
__device__ __forceinline__ void wait_flags_n(const unsigned* f, unsigned tgt,
                                             int tid, int n) {
  if (tid < n) {
    const unsigned* fp = f + tid * 16;
    unsigned v = __hip_atomic_load((unsigned*)fp, __ATOMIC_RELAXED,
                                   __HIP_MEMORY_SCOPE_AGENT);
    while (v < tgt) {
      __builtin_amdgcn_s_sleep(4);
      v = __hip_atomic_load((unsigned*)fp, __ATOMIC_RELAXED,
                            __HIP_MEMORY_SCOPE_AGENT);
    }
  }
  __atomic_signal_fence(__ATOMIC_SEQ_CST);
  __syncthreads();
}

__device__ __forceinline__ float red16(float v) {
  v += __shfl_xor(v, 1, 16);
  v += __shfl_xor(v, 2, 16);
  v += __shfl_xor(v, 4, 16);
  v += __shfl_xor(v, 8, 16);
  return v;
}

// 48-FMA chunk dot: weights from VGPR array W, data from LDS pointer PTR.
#define CDOT48(W, PTR, RES) do {                                              \
  const float* _p = (PTR);                                                    \
  float _a0 = 0.f, _a1 = 0.f, _a2 = 0.f, _a3 = 0.f;                           \
  _Pragma("unroll")                                                           \
  for (int _i = 0; _i < 48; _i += 16) {                                       \
    float4 _v0 = *(const float4*)(_p + _i);                                   \
    float4 _v1 = *(const float4*)(_p + _i + 4);                               \
    float4 _v2 = *(const float4*)(_p + _i + 8);                               \
    float4 _v3 = *(const float4*)(_p + _i + 12);                              \
    _a0 = fmaf((W)[_i + 0], _v0.x, _a0); _a0 = fmaf((W)[_i + 1], _v0.y, _a0); \
    _a0 = fmaf((W)[_i + 2], _v0.z, _a0); _a0 = fmaf((W)[_i + 3], _v0.w, _a0); \
    _a1 = fmaf((W)[_i + 4], _v1.x, _a1); _a1 = fmaf((W)[_i + 5], _v1.y, _a1); \
    _a1 = fmaf((W)[_i + 6], _v1.z, _a1); _a1 = fmaf((W)[_i + 7], _v1.w, _a1); \
    _a2 = fmaf((W)[_i + 8], _v2.x, _a2); _a2 = fmaf((W)[_i + 9], _v2.y, _a2); \
    _a2 = fmaf((W)[_i +10], _v2.z, _a2); _a2 = fmaf((W)[_i +11], _v2.w, _a2); \
    _a3 = fmaf((W)[_i +12], _v3.x, _a3); _a3 = fmaf((W)[_i +13], _v3.y, _a3); \
    _a3 = fmaf((W)[_i +14], _v3.z, _a3); _a3 = fmaf((W)[_i +15], _v3.w, _a3); \
  }                                                                           \
  RES = (_a0 + _a1) + (_a2 + _a3);                                            \
} while (0)

// h gather: global chunked [s][r][24 ull] is LDS-linear per chunk.
// 8 waves x 2 chunks x 3 loads.
#define STAGE_H(SRC, DSTF) do {                                              \
  const float4* _g = (const float4*)(const void*)(SRC);                      \
  _Pragma("unroll")                                                          \
  for (int _cc = 0; _cc < 2; ++_cc) {                                        \
    int _c = wv * 2 + _cc;                                                   \
    _Pragma("unroll")                                                        \
    for (int _k = 0; _k < 3; ++_k)                                           \
      gl2lds(_g + _c * 192 + _k * 64 + ln, (DSTF) + _c * 772 + _k * 256);    \
  }                                                                          \
} while (0)

// prev gather: global [b][88 ull] -> LDS [b][176] linear. 11 x 1KB regions.
#define STAGE_PREV(PAR) do {                                                 \
  const float4* _gp = (const float4*)(const void*)(prevg + (size_t)(PAR) * 1408); \
  _Pragma("unroll")                                                          \
  for (int _j = 0; _j < 11; ++_j)                                            \
    if (wv == (_j & 7))                                                      \
      gl2lds(_gp + _j * 64 + ln, prevs + _j * 256);                          \
} while (0)

// x gather: global [t][b][768] -> LDS chunked [s][b][48] (pad 4/chunk).
#define STAGE_X(T) do {                                                      \
  const float4* _gx = (const float4*)(aco + (size_t)(T) * 12288);            \
  _Pragma("unroll")                                                          \
  for (int _cc = 0; _cc < 2; ++_cc) {                                        \
    int _c = wv * 2 + _cc;                                                   \
    _Pragma("unroll")                                                        \
    for (int _k = 0; _k < 3; ++_k) {                                         \
      int _u = _k * 64 + ln;                                                 \
      int _b = _u / 12, _m = _u - _b * 12;                                   \
      gl2lds_nc(_gx + _b * 192 + _c * 12 + _m, bufA + _c * 772 + _k * 256);  \
    }                                                                        \
  }                                                                          \
} while (0)

// ---------------------------------------------------------------------------
// K1: fused conv1+bn1+relu -> conv2+bn2+relu -> pool(1,2). (unchanged)
// ---------------------------------------------------------------------------
__global__ __launch_bounds__(256) void conv12_kernel(
    const float* __restrict__ mel,
    const float* __restrict__ c1w, const float* __restrict__ c1b,
    const float* __restrict__ bn1g, const float* __restrict__ bn1b,
    const float* __restrict__ bn1m, const float* __restrict__ bn1v,
    const float* __restrict__ c2w, const float* __restrict__ c2b,
    const float* __restrict__ bn2g, const float* __restrict__ bn2b,
    const float* __restrict__ bn2m, const float* __restrict__ bn2v,
    float* __restrict__ A, int b0)
{
  __shared__ float melS[5 * 232];
  __shared__ float x1S[12 * 3 * 232];
  __shared__ float wS[48 * 12 * 9];
  const int tid = threadIdx.x;
  const int bl = blockIdx.x >> 9;
  const int b = b0 + bl;
  const int t = blockIdx.x & 511;

  for (int idx = tid; idx < 5 * 232; idx += 256) {
    int rr = idx / 232, cc = idx - rr * 232;
    int r = t - 2 + rr, w = cc - 1;
    float v = 0.f;
    if (r >= 0 && r < 512 && w >= 0 && w < 229) v = mel[(b * 512 + r) * 229 + w];
    melS[idx] = v;
  }

  float accA[22], accB[22];
#pragma unroll
  for (int i = 0; i < 22; ++i) { accA[i] = 0.f; accB[i] = 0.f; }
  __syncthreads();

  for (int icc = 0; icc < 4; ++icc) {
    if (icc) __syncthreads();
    for (int idx = tid; idx < 12 * 3 * 232; idx += 256) {
      int cl = idx / (3 * 232);
      int rem = idx - cl * (3 * 232);
      int rr = rem / 232, cc = rem - rr * 232;
      int c = icc * 12 + cl;
      int r1 = t - 1 + rr, w = cc - 1;
      float v = 0.f;
      if (r1 >= 0 && r1 < 512 && w >= 0 && w < 229) {
        const float* cw = c1w + c * 9;
        const float* m0 = melS + rr * 232 + cc - 1;
        float s = m0[0] * cw[0] + m0[1] * cw[1] + m0[2] * cw[2]
                + m0[232] * cw[3] + m0[233] * cw[4] + m0[234] * cw[5]
                + m0[464] * cw[6] + m0[465] * cw[7] + m0[466] * cw[8];
        s += c1b[c];
        float sc = bn1g[c] * rsqrtf(bn1v[c] + 1e-5f);
        v = fmaxf(s * sc + (bn1b[c] - bn1m[c] * sc), 0.f);
      }
      x1S[idx] = v;
    }
    for (int idx = tid; idx < 48 * 12 * 9; idx += 256) {
      int oc = idx / 108, rem = idx - oc * 108;
      wS[idx] = c2w[(oc * 48 + icc * 12) * 9 + rem];
    }
    __syncthreads();
    for (int i = 0; i < 22; ++i) {
      int oidx = tid + i * 256;
      if (oidx >= 5472) break;
      int oc = oidx / 114, wp = oidx - oc * 114;
      int w0 = 2 * wp;
      float a0 = accA[i], a1 = accB[i];
      const float* wp9 = wS + oc * 108;
      for (int icl = 0; icl < 12; ++icl) {
#pragma unroll
        for (int a = 0; a < 3; ++a) {
          const float* xr = x1S + (icl * 3 + a) * 232 + w0;
          float x0 = xr[0], x1 = xr[1], x2 = xr[2], x3 = xr[3];
          float wA = wp9[icl * 9 + a * 3 + 0];
          float wB = wp9[icl * 9 + a * 3 + 1];
          float wC = wp9[icl * 9 + a * 3 + 2];
          a0 = fmaf(x0, wA, a0); a0 = fmaf(x1, wB, a0); a0 = fmaf(x2, wC, a0);
          a1 = fmaf(x1, wA, a1); a1 = fmaf(x2, wB, a1); a1 = fmaf(x3, wC, a1);
        }
      }
      accA[i] = a0; accB[i] = a1;
    }
  }
  for (int i = 0; i < 22; ++i) {
    int oidx = tid + i * 256;
    if (oidx >= 5472) break;
    int oc = oidx / 114, wp = oidx - oc * 114;
    float sc = bn2g[oc] * rsqrtf(bn2v[oc] + 1e-5f);
    float sh = bn2b[oc] - bn2m[oc] * sc;
    float v0 = fmaxf((accA[i] + c2b[oc]) * sc + sh, 0.f);
    float v1 = fmaxf((accB[i] + c2b[oc]) * sc + sh, 0.f);
    A[((bl * 48 + oc) * 512 + t) * 114 + wp] = fmaxf(v0, v1);
  }
}

// ---------------------------------------------------------------------------
// K2: conv3+bn3+relu+pool(1,2); GEMM-ready output. (unchanged)
// ---------------------------------------------------------------------------
__global__ __launch_bounds__(256) void conv3_kernel(
    const float* __restrict__ A,
    const float* __restrict__ c3w, const float* __restrict__ c3b,
    const float* __restrict__ bn3g, const float* __restrict__ bn3b,
    const float* __restrict__ bn3m, const float* __restrict__ bn3v,
    float* __restrict__ Bf)
{
  __shared__ float aS[16 * 3 * 116];
  __shared__ float wS[48 * 16 * 9];
  const int tid = threadIdx.x;
  const int bl = blockIdx.x / 510;
  const int t = blockIdx.x - bl * 510;

  for (int ocg = 0; ocg < 2; ++ocg) {
    float accA[11], accB[11];
#pragma unroll
    for (int i = 0; i < 11; ++i) { accA[i] = 0.f; accB[i] = 0.f; }
    for (int icc = 0; icc < 3; ++icc) {
      __syncthreads();
      for (int idx = tid; idx < 16 * 3 * 116; idx += 256) {
        int cl = idx / 348, rem = idx - cl * 348;
        int rr = rem / 116, cc = rem - rr * 116;
        int w = cc - 1;
        float v = 0.f;
        if (w >= 0 && w < 114) v = A[((bl * 48 + icc * 16 + cl) * 512 + t + rr) * 114 + w];
        aS[idx] = v;
      }
      for (int idx = tid; idx < 48 * 16 * 9; idx += 256) {
        int ocl = idx / 144, rem = idx - ocl * 144;
        wS[idx] = c3w[((ocg * 48 + ocl) * 48 + icc * 16) * 9 + rem];
      }
      __syncthreads();
      for (int i = 0; i < 11; ++i) {
        int oidx = tid + i * 256;
        if (oidx >= 2736) break;
        int ocl = oidx / 57, wp = oidx - ocl * 57;
        int w0 = 2 * wp;
        float a0 = accA[i], a1 = accB[i];
        const float* wb = wS + ocl * 144;
        for (int icl = 0; icl < 16; ++icl) {
#pragma unroll
          for (int a = 0; a < 3; ++a) {
            const float* xr = aS + (icl * 3 + a) * 116 + w0;
            float x0 = xr[0], x1 = xr[1], x2 = xr[2], x3 = xr[3];
            float wA = wb[icl * 9 + a * 3 + 0];
            float wB = wb[icl * 9 + a * 3 + 1];
            float wC = wb[icl * 9 + a * 3 + 2];
            a0 = fmaf(x0, wA, a0); a0 = fmaf(x1, wB, a0); a0 = fmaf(x2, wC, a0);
            a1 = fmaf(x1, wA, a1); a1 = fmaf(x2, wB, a1); a1 = fmaf(x3, wC, a1);
          }
        }
        accA[i] = a0; accB[i] = a1;
      }
    }
    for (int i = 0; i < 11; ++i) {
      int oidx = tid + i * 256;
      if (oidx >= 2736) break;
      int ocl = oidx / 57, wp = oidx - ocl * 57;
      int oc = ocg * 48 + ocl;
      float sc = bn3g[oc] * rsqrtf(bn3v[oc] + 1e-5f);
      float sh = bn3b[oc] - bn3m[oc] * sc;
      float v0 = fmaxf((accA[i] + c3b[oc]) * sc + sh, 0.f);
      float v1 = fmaxf((accB[i] + c3b[oc]) * sc + sh, 0.f);
      Bf[(size_t)(bl * 510 + t) * 5472 + oc * 57 + wp] = fmaxf(v0, v1);
    }
  }
}

// ---------------------------------------------------------------------------
// K3: fp32 NT GEMM  C = A * B^T + bias, output relaid to [t][16][768].
// ---------------------------------------------------------------------------
__global__ __launch_bounds__(256) void gemm_nt(
    const float* __restrict__ Am, const float* __restrict__ Bm,
    const float* __restrict__ bias, float* __restrict__ C,
    int M, int K, int lda, int ldb, int b0)
{
  __shared__ float As[64 * 33];
  __shared__ float Bs[64 * 33];
  const int tid = threadIdx.x;
  const int m0 = blockIdx.x * 64, n0 = blockIdx.y * 64;
  const int tx = tid & 15, ty = tid >> 4;
  const int kq = (tid & 7) * 4, rw = tid >> 3;
  float acc[4][4];
#pragma unroll
  for (int i = 0; i < 4; ++i)
#pragma unroll
    for (int j = 0; j < 4; ++j) acc[i][j] = 0.f;

  for (int k0 = 0; k0 < K; k0 += 32) {
    int m1 = m0 + rw, m2 = m1 + 32;
    float4 va = make_float4(0.f, 0.f, 0.f, 0.f), vb = va;
    if (m1 < M) va = *(const float4*)(Am + (size_t)m1 * lda + k0 + kq);
    if (m2 < M) vb = *(const float4*)(Am + (size_t)m2 * lda + k0 + kq);
    float4 wa = *(const float4*)(Bm + (size_t)(n0 + rw) * ldb + k0 + kq);
    float4 wb = *(const float4*)(Bm + (size_t)(n0 + rw + 32) * ldb + k0 + kq);
    As[rw * 33 + kq + 0] = va.x; As[rw * 33 + kq + 1] = va.y;
    As[rw * 33 + kq + 2] = va.z; As[rw * 33 + kq + 3] = va.w;
    As[(rw + 32) * 33 + kq + 0] = vb.x; As[(rw + 32) * 33 + kq + 1] = vb.y;
    As[(rw + 32) * 33 + kq + 2] = vb.z; As[(rw + 32) * 33 + kq + 3] = vb.w;
    Bs[rw * 33 + kq + 0] = wa.x; Bs[rw * 33 + kq + 1] = wa.y;
    Bs[rw * 33 + kq + 2] = wa.z; Bs[rw * 33 + kq + 3] = wa.w;
    Bs[(rw + 32) * 33 + kq + 0] = wb.x; Bs[(rw + 32) * 33 + kq + 1] = wb.y;
    Bs[(rw + 32) * 33 + kq + 2] = wb.z; Bs[(rw + 32) * 33 + kq + 3] = wb.w;
    __syncthreads();
#pragma unroll 8
    for (int k = 0; k < 32; ++k) {
      float av[4], bv[4];
#pragma unroll
      for (int i = 0; i < 4; ++i) av[i] = As[(ty * 4 + i) * 33 + k];
#pragma unroll
      for (int j = 0; j < 4; ++j) bv[j] = Bs[(tx * 4 + j) * 33 + k];
#pragma unroll
      for (int i = 0; i < 4; ++i)
#pragma unroll
        for (int j = 0; j < 4; ++j) acc[i][j] = fmaf(av[i], bv[j], acc[i][j]);
    }
    __syncthreads();
  }
#pragma unroll
  for (int i = 0; i < 4; ++i) {
    int m = m0 + ty * 4 + i;
    if (m >= M) continue;
    int bl2 = m / 510, tt2 = m - bl2 * 510;
    float* crow = C + ((size_t)tt2 * 16 + (b0 + bl2)) * 768;
#pragma unroll
    for (int j = 0; j < 4; ++j) {
      int n = n0 + tx * 4 + j;
      crow[n] = acc[i][j] + bias[n];
    }
  }
}

// ---------------------------------------------------------------------------
__global__ void init_state(ull* __restrict__ h1g, ull* __restrict__ h2g,
                           ull* __restrict__ prevg, unsigned* __restrict__ bar) {
  int gid = blockIdx.x * 256 + threadIdx.x;
  if (gid < 12288) { at_store(h1g + gid, 0ull); at_store(h2g + gid, 0ull); }
  if (gid < 2816) at_store(prevg + gid, 0ull);
  if (gid < BAR_U32)
    __hip_atomic_store(bar + gid, 0u, __ATOMIC_RELAXED, __HIP_MEMORY_SCOPE_AGENT);
}

// ---------------------------------------------------------------------------
// K6: persistent LSTM. 96 compute blocks (512t, 8 dims) + 22 proj blocks
// (512t, 20 rows). r11 scheduling; coherent gload_lds gathers.
// ---------------------------------------------------------------------------
__global__ __launch_bounds__(512, 2) void lstm_kernel(
    const float* __restrict__ aco,   // [510][16][768]
    const float* __restrict__ whh0,  // [3072][768]
    const float* __restrict__ wih0,  // [3072][944]
    const float* __restrict__ wih1,  // [3072][768]
    const float* __restrict__ whh1,  // [3072][768]
    const float* __restrict__ bih0, const float* __restrict__ bhh0,
    const float* __restrict__ bih1, const float* __restrict__ bhh1,
    const float* __restrict__ pw,    // [440][768]
    const float* __restrict__ pb,
    const float* __restrict__ emb,   // [5][2]
    ull* __restrict__ h1g,           // [2][6144] chunked
    ull* __restrict__ h2g,           // [2][6144] chunked
    ull* __restrict__ prevg,         // [2][16][88]
    unsigned* __restrict__ bar,
    float* __restrict__ out)         // [16][510][440]
{
  __shared__ float bufA[16 * 772];   // x (compute) / h2 (proj)
  __shared__ float bufB[16 * 772];   // h1
  __shared__ float bufC[16 * 772];   // h2(t-1)
  __shared__ float prevs[16 * 176];  // [b][176]
  __shared__ float zl[32 * 17];
  __shared__ float embS[10];
  const int tid = threadIdx.x;
  const int s = tid & 15;
  const int r = tid >> 4;            // 0..31
  const int wv = tid >> 6;           // 0..7
  const int ln = tid & 63;
  unsigned* f1 = bar + F1_OFF;
  unsigned* f2 = bar + F2_OFF;
  unsigned* fpf = bar + FP_OFF;

  if (blockIdx.x < NCOMP) {
    // =======================================================================
    // COMPUTE BLOCK: 8 hidden dims (both layers), all 16 batches.
    // rows: r = g*8 + d  (g=gate, d=dim-in-block)
    // =======================================================================
    const int uB = blockIdx.x * 8;
    const int j = (r >> 3) * 768 + uB + (r & 7);

    float wx[48], w0[48], w1[48], w2[48], wp[11];
    {
      const float* p = wih0 + (size_t)j * 944 + 48 * s;
#pragma unroll
      for (int i = 0; i < 48; i += 4) {
        float4 v = *(const float4*)(p + i);
        wx[i] = v.x; wx[i+1] = v.y; wx[i+2] = v.z; wx[i+3] = v.w;
      }
      p = whh0 + (size_t)j * 768 + 48 * s;
#pragma unroll
      for (int i = 0; i < 48; i += 4) {
        float4 v = *(const float4*)(p + i);
        w0[i] = v.x; w0[i+1] = v.y; w0[i+2] = v.z; w0[i+3] = v.w;
      }
      p = wih1 + (size_t)j * 768 + 48 * s;
#pragma unroll
      for (int i = 0; i < 48; i += 4) {
        float4 v = *(const float4*)(p + i);
        w1[i] = v.x; w1[i+1] = v.y; w1[i+2] = v.z; w1[i+3] = v.w;
      }
      p = whh1 + (size_t)j * 768 + 48 * s;
#pragma unroll
      for (int i = 0; i < 48; i += 4) {
        float4 v = *(const float4*)(p + i);
        w2[i] = v.x; w2[i+1] = v.y; w2[i+2] = v.z; w2[i+3] = v.w;
      }
      const float* pp = wih0 + (size_t)j * 944 + 768 + 11 * s;
#pragma unroll
      for (int i = 0; i < 11; ++i) wp[i] = pp[i];
    }
    // cell thread state: wave 0, 2 dims/thread (ul and ul+4)
    float bl1a[4], bl1b[4], bl2a[4], bl2b[4];
    float c1a = 0.f, c1b = 0.f, c2a = 0.f, c2b = 0.f;
    if (tid < 64) {
      int ul = tid >> 4;
#pragma unroll
      for (int g = 0; g < 4; ++g) {
        int ja = g * 768 + uB + ul;
        int jb = ja + 4;
        bl1a[g] = bih0[ja] + bhh0[ja];
        bl1b[g] = bih0[jb] + bhh0[jb];
        bl2a[g] = bih1[ja] + bhh1[ja];
        bl2b[g] = bih1[jb] + bhh1[jb];
      }
    }
    // publish base: dims uB..uB+7 = chunk s2, ull slots q0..q0+3
    const int s2 = uB / 48;
    const int q0 = (uB % 48) >> 1;
    const int hb0 = s2 * 384 + q0;

    // h1(-1) = 0 in bufB
    for (int i = tid; i < 16 * 772; i += 512) bufB[i] = 0.f;

    // prologue: x(0) stage + dot
    float zxr[16];
    STAGE_X(0);
    __syncthreads();
#pragma unroll 4
    for (int b = 0; b < 16; ++b) {
      float p; CDOT48(wx, bufA + s * 772 + b * 48, p);
      zxr[b] = red16(p);
    }

    for (int t = 0; t < 510; ++t) {
      const int wbuf = t & 1, rbuf = wbuf ^ 1;
      __syncthreads();
      // ---- issue x(t+1) stage early; drains at the next barrier ----
      if (t < 509) STAGE_X(t + 1);
      // ---- w0 dot: bufB = h1(t-1) (overlaps proj blocks' step t-1) ----
#pragma unroll 4
      for (int b = 0; b < 16; ++b) {
        float p; CDOT48(w0, bufB + s * 772 + b * 48, p);
        p = red16(p);
        if (s == 0) zl[r * 17 + b] = zxr[b] + p;
      }
      // ---- prev(t-1) ready: all 22 proj flags >= t ----
      if (t) wait_flags_n(fpf, (unsigned)t, tid, NPROJ);
      else __syncthreads();
      // ---- prefetch h2(t-1) -> bufC; stage prev (prevg init-zeroed) ----
      STAGE_H(h2g + rbuf * 6144, bufC);
      STAGE_PREV(rbuf);
      __syncthreads();
#pragma unroll 4
      for (int b = 0; b < 16; ++b) {
        const float* pvv = prevs + b * 176 + s * 11;
        float p = 0.f;
#pragma unroll
        for (int i = 0; i < 11; ++i) p = fmaf(wp[i], pvv[i], p);
        p = red16(p);
        if (s == 0) zl[r * 17 + b] += p;
      }
      __syncthreads();
      // ---- cell 1 (2 dims/thread) + shfl publish, wave 0 only ----
      if (tid < 64) {
        int ul = tid >> 4, bb = tid & 15;
        float zia = zl[(0 * 8 + ul) * 17 + bb] + bl1a[0];
        float zfa = zl[(1 * 8 + ul) * 17 + bb] + bl1a[1];
        float zga = zl[(2 * 8 + ul) * 17 + bb] + bl1a[2];
        float zoa = zl[(3 * 8 + ul) * 17 + bb] + bl1a[3];
        c1a = sigf(zfa) * c1a + sigf(zia) * tanhf(zga);
        float ha = sigf(zoa) * tanhf(c1a);
        float zib = zl[(0 * 8 + ul + 4) * 17 + bb] + bl1b[0];
        float zfb = zl[(1 * 8 + ul + 4) * 17 + bb] + bl1b[1];
        float zgb = zl[(2 * 8 + ul + 4) * 17 + bb] + bl1b[2];
        float zob = zl[(3 * 8 + ul + 4) * 17 + bb] + bl1b[3];
        c1b = sigf(zfb) * c1b + sigf(zib) * tanhf(zgb);
        float hb = sigf(zob) * tanhf(c1b);
        // writer (qq=ul): dims 2ul, 2ul+1
        int sl1 = ((2 * ul) & 3) * 16 + bb;
        int sl2 = ((2 * ul + 1) & 3) * 16 + bb;
        float a1 = __shfl(ha, sl1, 64), b1 = __shfl(hb, sl1, 64);
        float a2 = __shfl(ha, sl2, 64), b2 = __shfl(hb, sl2, 64);
        float v1 = (ul < 2) ? a1 : b1;
        float v2 = (ul < 2) ? a2 : b2;
        at_store(h1g + wbuf * 6144 + hb0 + bb * 24 + ul, pack2(v1, v2));
        if (tid == 0) {
          __builtin_amdgcn_s_waitcnt(0);
          __atomic_signal_fence(__ATOMIC_SEQ_CST);
          __hip_atomic_store(f1 + blockIdx.x * 16, (unsigned)(t + 1),
                             __ATOMIC_RELAXED, __HIP_MEMORY_SCOPE_AGENT);
        }
      }
      // ---- wx dot for t+1 fills the f1 window (bufA staged) ----
      if (t < 509) {
#pragma unroll 4
        for (int b = 0; b < 16; ++b) {
          float p; CDOT48(wx, bufA + s * 772 + b * 48, p);
          zxr[b] = red16(p);
        }
      }
      // ---- f1 wait, stage h1(t), fused w1/w2 dot ----
      wait_flags_n(f1, (unsigned)(t + 1), tid, NCOMP);
      STAGE_H(h1g + wbuf * 6144, bufB);
      __syncthreads();
#pragma unroll 2
      for (int b = 0; b < 16; ++b) {
        float p1, p2;
        CDOT48(w1, bufB + s * 772 + b * 48, p1);
        CDOT48(w2, bufC + s * 772 + b * 48, p2);
        float p = red16(p1 + p2);
        if (s == 0) zl[r * 17 + b] = p;
      }
      __syncthreads();
      // ---- cell 2 + shfl publish ----
      if (tid < 64) {
        int ul = tid >> 4, bb = tid & 15;
        float zia = zl[(0 * 8 + ul) * 17 + bb] + bl2a[0];
        float zfa = zl[(1 * 8 + ul) * 17 + bb] + bl2a[1];
        float zga = zl[(2 * 8 + ul) * 17 + bb] + bl2a[2];
        float zoa = zl[(3 * 8 + ul) * 17 + bb] + bl2a[3];
        c2a = sigf(zfa) * c2a + sigf(zia) * tanhf(zga);
        float ha = sigf(zoa) * tanhf(c2a);
        float zib = zl[(0 * 8 + ul + 4) * 17 + bb] + bl2b[0];
        float zfb = zl[(1 * 8 + ul + 4) * 17 + bb] + bl2b[1];
        float zgb = zl[(2 * 8 + ul + 4) * 17 + bb] + bl2b[2];
        float zob = zl[(3 * 8 + ul + 4) * 17 + bb] + bl2b[3];
        c2b = sigf(zfb) * c2b + sigf(zib) * tanhf(zgb);
        float hb = sigf(zob) * tanhf(c2b);
        int sl1 = ((2 * ul) & 3) * 16 + bb;
        int sl2 = ((2 * ul + 1) & 3) * 16 + bb;
        float a1 = __shfl(ha, sl1, 64), b1 = __shfl(hb, sl1, 64);
        float a2 = __shfl(ha, sl2, 64), b2 = __shfl(hb, sl2, 64);
        float v1 = (ul < 2) ? a1 : b1;
        float v2 = (ul < 2) ? a2 : b2;
        at_store(h2g + wbuf * 6144 + hb0 + bb * 24 + ul, pack2(v1, v2));
        if (tid == 0) {
          __builtin_amdgcn_s_waitcnt(0);
          __atomic_signal_fence(__ATOMIC_SEQ_CST);
          __hip_atomic_store(f2 + blockIdx.x * 16, (unsigned)(t + 1),
                             __ATOMIC_RELAXED, __HIP_MEMORY_SCOPE_AGENT);
        }
      }
    }
  } else {
    // =======================================================================
    // PROJECTION BLOCK: 20 logit rows (4 argmax groups), all 16 batches.
    // =======================================================================
    const int bp = blockIdx.x - NCOMP;   // 0..21
    const int prow = bp * 20 + r;        // valid for r < 20
    float pwr[48];
    float pbv = 0.f;
    if (r < 20) {
      const float* p = pw + (size_t)prow * 768 + 48 * s;
#pragma unroll
      for (int i = 0; i < 48; i += 4) {
        float4 v = *(const float4*)(p + i);
        pwr[i] = v.x; pwr[i+1] = v.y; pwr[i+2] = v.z; pwr[i+3] = v.w;
      }
      pbv = pb[prow];
    } else {
#pragma unroll
      for (int i = 0; i < 48; ++i) pwr[i] = 0.f;
    }
    if (tid < 10) embS[tid] = emb[tid];
    __syncthreads();

    for (int t = 0; t < 510; ++t) {
      const int wbuf = t & 1;
      wait_flags_n(f2, (unsigned)(t + 1), tid, NCOMP);
      STAGE_H(h2g + wbuf * 6144, bufA);
      __syncthreads();
#pragma unroll 4
      for (int b = 0; b < 16; ++b) {
        float p; CDOT48(pwr, bufA + s * 772 + b * 48, p);
        p = red16(p);
        if (r < 20 && s == 0) {
          float lg = p + pbv;
          out[((size_t)b * 510 + t) * 440 + prow] = lg;
          zl[r * 17 + b] = lg;
        }
      }
      __syncthreads();
      if (tid < 64) {
        int q = tid >> 4, bb = tid & 15;   // 4 argmax groups
        float best = zl[(q * 5) * 17 + bb]; int bi = 0;
#pragma unroll
        for (int c = 1; c < 5; ++c) {
          float v = zl[(q * 5 + c) * 17 + bb];
          if (v > best) { best = v; bi = c; }
        }
        at_store(prevg + wbuf * 1408 + bb * 88 + bp * 4 + q,
                 pack2(embS[bi * 2], embS[bi * 2 + 1]));
        if (tid == 0) {
          __builtin_amdgcn_s_waitcnt(0);
          __atomic_signal_fence(__ATOMIC_SEQ_CST);
          __hip_atomic_store(fpf + bp * 16, (unsigned)(t + 1),
                             __ATOMIC_RELAXED, __HIP_MEMORY_SCOPE_AGENT);
        }
      }
    }
  }
}

// ---------------------------------------------------------------------------
extern "C" void kernel_launch(void* const* d_in, const int* in_sizes, int n_in,
                              void* d_out, int out_size, void* d_ws, size_t ws_size,
                              hipStream_t stream) {
  (void)in_sizes; (void)n_in; (void)out_size;
  const float* mel  = (const float*)d_in[0];
  const float* c1w  = (const float*)d_in[1];
  const float* c1b  = (const float*)d_in[2];
  const float* c2w  = (const float*)d_in[3];
  const float* c2b  = (const float*)d_in[4];
  const float* c3w  = (const float*)d_in[5];
  const float* c3b  = (const float*)d_in[6];
  const float* bn1g = (const float*)d_in[7];
  const float* bn1b = (const float*)d_in[8];
  const float* bn1m = (const float*)d_in[9];
  const float* bn1v = (const float*)d_in[10];
  const float* bn2g = (const float*)d_in[11];
  const float* bn2b = (const float*)d_in[12];
  const float* bn2m = (const float*)d_in[13];
  const float* bn2v = (const float*)d_in[14];
  const float* bn3g = (const float*)d_in[15];
  const float* bn3b = (const float*)d_in[16];
  const float* bn3m = (const float*)d_in[17];
  const float* bn3v = (const float*)d_in[18];
  const float* fcw  = (const float*)d_in[19];
  const float* fcb  = (const float*)d_in[20];
  const float* wih0 = (const float*)d_in[21];
  const float* whh0 = (const float*)d_in[22];
  const float* bih0 = (const float*)d_in[23];
  const float* bhh0 = (const float*)d_in[24];
  const float* wih1 = (const float*)d_in[25];
  const float* whh1 = (const float*)d_in[26];
  const float* bih1 = (const float*)d_in[27];
  const float* bhh1 = (const float*)d_in[28];
  const float* pw   = (const float*)d_in[29];
  const float* pb   = (const float*)d_in[30];
  const float* emb  = (const float*)d_in[31];

  float* ws = (float*)d_ws;
  float* outp = (float*)d_out;

  const size_t ST_ULL = 12288ull + 12288ull + 2816ull;
  int CB = 1;
  for (int cb = 4; cb >= 1; cb >>= 1) {
    size_t need = (ACO_FL + (size_t)cb * 48 * 512 * 114 + (size_t)cb * 510 * 5472) * 4
                + ST_ULL * 8 + BAR_U32 * 4 + 1024;
    if (ws_size >= need) { CB = cb; break; }
  }
  const int nchunks = 16 / CB;
  const size_t A_FL  = (size_t)CB * 48 * 512 * 114;
  const size_t BF_FL = (size_t)CB * 510 * 5472;

  float* aco = ws;                       // [510][16][768]
  float* Ac  = ws + ACO_FL;
  float* Bfc = Ac + A_FL;
  ull* h1g   = (ull*)(Bfc + BF_FL);
  ull* h2g   = h1g + 12288;
  ull* prevg = h2g + 12288;
  unsigned* bar = (unsigned*)(prevg + 2816);

  for (int ch = 0; ch < nchunks; ++ch) {
    int b0 = ch * CB;
    hipLaunchKernelGGL(conv12_kernel, dim3(CB * 512), dim3(256), 0, stream,
                       mel, c1w, c1b, bn1g, bn1b, bn1m, bn1v,
                       c2w, c2b, bn2g, bn2b, bn2m, bn2v, Ac, b0);
    hipLaunchKernelGGL(conv3_kernel, dim3(CB * 510), dim3(256), 0, stream,
                       Ac, c3w, c3b, bn3g, bn3b, bn3m, bn3v, Bfc);
    int M = CB * 510;
    hipLaunchKernelGGL(gemm_nt, dim3((M + 63) / 64, 12), dim3(256), 0, stream,
                       Bfc, fcw, fcb, aco, M, 5472, 5472, 5472, b0);
  }
  hipLaunchKernelGGL(init_state, dim3(48), dim3(256), 0, stream,
                     h1g, h2g, prevg, bar);

  {
    void* args[] = {
      (void*)&aco, (void*)&whh0, (void*)&wih0, (void*)&wih1, (void*)&whh1,
      (void*)&bih0, (void*)&bhh0, (void*)&bih1, (void*)&bhh1,
      (void*)&pw, (void*)&pb, (void*)&emb,
      (void*)&h1g, (void*)&h2g, (void*)&prevg, (void*)&bar, (void*)&outp
    };
    hipError_t e = hipLaunchCooperativeKernel((const void*)lstm_kernel,
                                              dim3(NCOMP + NPROJ), dim3(512),
                                              args, 0, stream);
    if (e != hipSuccess) {
      (void)hipGetLastError();
      hipLaunchKernelGGL(lstm_kernel, dim3(NCOMP + NPROJ), dim3(512), 0, stream,
                         aco, whh0, wih0, wih1, whh1, bih0, bhh0, bih1, bhh1,
                         pw, pb, emb, h1g, h2g, prevg, bar, outp);
    }
  }
}

// Round 9
// 25141.621 us; speedup vs baseline: 1.1890x; 1.1890x over previous
//
#include <hip/hip_runtime.h>
#include <math.h>

// ============================================================================
// AR_Transcriber round 14.
// r12 (inline proj) and r13 (512t/fewer blocks) BOTH regressed -> coherent
// traffic volume is NOT the limiter. REVERT to r11 (best: 17.0ms steady).
// Remaining model: rendezvous straggler skew (3 max-of-192 waits/step).
// This round = r11 + dot RE-SCHEDULING only:
//  1. Direct f2-wait (1 step slack, near-free) -> stage bufC early ->
//     w2-dot runs BEFORE the fpf(prev) wait, giving the proj chain ~1.5us
//     more cover.
//  2. Post-f1 path = stage h1 + w1-only dot (+zl2 add): -1.5us serial tail.
//  3. Everything else identical to r11 (layouts, flags, proj role split,
//     backoff polling, shfl publish, coherent gload_lds gathers).
// ============================================================================

typedef unsigned long long ull;

#define ACO_FL 6266880ull  // 510*16*768
#define F1_OFF 0           // 192 flags * 16 u32 stride
#define F2_OFF 3072
#define FP_OFF 6144        // 44 proj flags * 16 u32 stride
#define BAR_U32 8192
#define NCOMP 192
#define NPROJ 44

__device__ __forceinline__ float sigf(float x) { return 1.0f / (1.0f + expf(-x)); }

__device__ __forceinline__ ull pack2(float x, float y) {
  union { float f[2]; ull u; } c; c.f[0] = x; c.f[1] = y; return c.u;
}
__device__ __forceinline__ ull at_load(const ull* p) {
  return __hip_atomic_load((ull*)p, __ATOMIC_RELAXED, __HIP_MEMORY_SCOPE_AGENT);
}
__device__ __forceinline__ void at_store(ull* p, ull v) {
  __hip_atomic_store(p, v, __ATOMIC_RELAXED, __HIP_MEMORY_SCOPE_AGENT);
}

// Device-coherent (sc0|sc1 = 17) global -> LDS direct copy, 16B/lane.
__device__ __forceinline__ void gl2lds(const float4* g, float* l) {
  __builtin_amdgcn_global_load_lds(
      (const __attribute__((address_space(1))) void*)(g),
      (__attribute__((address_space(3))) void*)(l), 16, 0, 17);
}
// Cached variant (input written by a prior dispatch).
__device__ __forceinline__ void gl2lds_nc(const float4* g, float* l) {
  __builtin_amdgcn_global_load_lds(
      (const __attribute__((address_space(1))) void*)(g),
      (__attribute__((address_space(3))) void*)(l), 16, 0, 0);
}

// Parallel per-producer flag wait with backoff: thread tid<n polls line tid.
__device__ __forceinline__ void wait_flags_n(const unsigned* f, unsigned tgt,
                                             int tid, int n) {
  if (tid < n) {
    const unsigned* fp = f + tid * 16;
    unsigned v = __hip_atomic_load((unsigned*)fp, __ATOMIC_RELAXED,
                                   __HIP_MEMORY_SCOPE_AGENT);
    while (v < tgt) {
      __builtin_amdgcn_s_sleep(4);
      v = __hip_atomic_load((unsigned*)fp, __ATOMIC_RELAXED,
                            __HIP_MEMORY_SCOPE_AGENT);
    }
  }
  __atomic_signal_fence(__ATOMIC_SEQ_CST);
  __syncthreads();
}

__device__ __forceinline__ float red16(float v) {
  v += __shfl_xor(v, 1, 16);
  v += __shfl_xor(v, 2, 16);
  v += __shfl_xor(v, 4, 16);
  v += __shfl_xor(v, 8, 16);
  return v;
}

// 48-FMA chunk dot: weights from VGPR array W, data from LDS pointer PTR.
#define CDOT48(W, PTR, RES) do {                                              \
  const float* _p = (PTR);                                                    \
  float _a0 = 0.f, _a1 = 0.f, _a2 = 0.f, _a3 = 0.f;                           \
  _Pragma("unroll")                                                           \
  for (int _i = 0; _i < 48; _i += 16) {                                       \
    float4 _v0 = *(const float4*)(_p + _i);                                   \
    float4 _v1 = *(const float4*)(_p + _i + 4);                               \
    float4 _v2 = *(const float4*)(_p + _i + 8);                               \
    float4 _v3 = *(const float4*)(_p + _i + 12);                              \
    _a0 = fmaf((W)[_i + 0], _v0.x, _a0); _a0 = fmaf((W)[_i + 1], _v0.y, _a0); \
    _a0 = fmaf((W)[_i + 2], _v0.z, _a0); _a0 = fmaf((W)[_i + 3], _v0.w, _a0); \
    _a1 = fmaf((W)[_i + 4], _v1.x, _a1); _a1 = fmaf((W)[_i + 5], _v1.y, _a1); \
    _a1 = fmaf((W)[_i + 6], _v1.z, _a1); _a1 = fmaf((W)[_i + 7], _v1.w, _a1); \
    _a2 = fmaf((W)[_i + 8], _v2.x, _a2); _a2 = fmaf((W)[_i + 9], _v2.y, _a2); \
    _a2 = fmaf((W)[_i +10], _v2.z, _a2); _a2 = fmaf((W)[_i +11], _v2.w, _a2); \
    _a3 = fmaf((W)[_i +12], _v3.x, _a3); _a3 = fmaf((W)[_i +13], _v3.y, _a3); \
    _a3 = fmaf((W)[_i +14], _v3.z, _a3); _a3 = fmaf((W)[_i +15], _v3.w, _a3); \
  }                                                                           \
  RES = (_a0 + _a1) + (_a2 + _a3);                                            \
} while (0)

// h gather: global chunked [s][r][24 ull] is LDS-linear per chunk.
#define STAGE_H(SRC, DSTF) do {                                              \
  const float4* _g = (const float4*)(const void*)(SRC);                      \
  _Pragma("unroll")                                                          \
  for (int _cc = 0; _cc < 4; ++_cc) {                                        \
    int _c = wv * 4 + _cc;                                                   \
    _Pragma("unroll")                                                        \
    for (int _k = 0; _k < 3; ++_k)                                           \
      gl2lds(_g + _c * 192 + _k * 64 + ln, (DSTF) + _c * 772 + _k * 256);    \
  }                                                                          \
} while (0)

// prev gather: global [b][88 ull] -> LDS [b][176] linear.
#define STAGE_PREV(PAR) do {                                                 \
  const float4* _gp = (const float4*)(const void*)(prevg + (size_t)(PAR) * 1408); \
  _Pragma("unroll")                                                          \
  for (int _j = 0; _j < 11; ++_j)                                            \
    if (wv == (_j & 3))                                                      \
      gl2lds(_gp + _j * 64 + ln, prevs + _j * 256);                          \
} while (0)

// x gather: global [t][b][768] -> LDS chunked [s][b][48] (pad 4/chunk).
#define STAGE_X(T) do {                                                      \
  const float4* _gx = (const float4*)(aco + (size_t)(T) * 12288);            \
  _Pragma("unroll")                                                          \
  for (int _cc = 0; _cc < 4; ++_cc) {                                        \
    int _c = wv * 4 + _cc;                                                   \
    _Pragma("unroll")                                                        \
    for (int _k = 0; _k < 3; ++_k) {                                         \
      int _u = _k * 64 + ln;                                                 \
      int _b = _u / 12, _m = _u - _b * 12;                                   \
      gl2lds_nc(_gx + _b * 192 + _c * 12 + _m, bufA + _c * 772 + _k * 256);  \
    }                                                                        \
  }                                                                          \
} while (0)

// ---------------------------------------------------------------------------
// K1: fused conv1+bn1+relu -> conv2+bn2+relu -> pool(1,2). (unchanged)
// ---------------------------------------------------------------------------
__global__ __launch_bounds__(256) void conv12_kernel(
    const float* __restrict__ mel,
    const float* __restrict__ c1w, const float* __restrict__ c1b,
    const float* __restrict__ bn1g, const float* __restrict__ bn1b,
    const float* __restrict__ bn1m, const float* __restrict__ bn1v,
    const float* __restrict__ c2w, const float* __restrict__ c2b,
    const float* __restrict__ bn2g, const float* __restrict__ bn2b,
    const float* __restrict__ bn2m, const float* __restrict__ bn2v,
    float* __restrict__ A, int b0)
{
  __shared__ float melS[5 * 232];
  __shared__ float x1S[12 * 3 * 232];
  __shared__ float wS[48 * 12 * 9];
  const int tid = threadIdx.x;
  const int bl = blockIdx.x >> 9;
  const int b = b0 + bl;
  const int t = blockIdx.x & 511;

  for (int idx = tid; idx < 5 * 232; idx += 256) {
    int rr = idx / 232, cc = idx - rr * 232;
    int r = t - 2 + rr, w = cc - 1;
    float v = 0.f;
    if (r >= 0 && r < 512 && w >= 0 && w < 229) v = mel[(b * 512 + r) * 229 + w];
    melS[idx] = v;
  }

  float accA[22], accB[22];
#pragma unroll
  for (int i = 0; i < 22; ++i) { accA[i] = 0.f; accB[i] = 0.f; }
  __syncthreads();

  for (int icc = 0; icc < 4; ++icc) {
    if (icc) __syncthreads();
    for (int idx = tid; idx < 12 * 3 * 232; idx += 256) {
      int cl = idx / (3 * 232);
      int rem = idx - cl * (3 * 232);
      int rr = rem / 232, cc = rem - rr * 232;
      int c = icc * 12 + cl;
      int r1 = t - 1 + rr, w = cc - 1;
      float v = 0.f;
      if (r1 >= 0 && r1 < 512 && w >= 0 && w < 229) {
        const float* cw = c1w + c * 9;
        const float* m0 = melS + rr * 232 + cc - 1;
        float s = m0[0] * cw[0] + m0[1] * cw[1] + m0[2] * cw[2]
                + m0[232] * cw[3] + m0[233] * cw[4] + m0[234] * cw[5]
                + m0[464] * cw[6] + m0[465] * cw[7] + m0[466] * cw[8];
        s += c1b[c];
        float sc = bn1g[c] * rsqrtf(bn1v[c] + 1e-5f);
        v = fmaxf(s * sc + (bn1b[c] - bn1m[c] * sc), 0.f);
      }
      x1S[idx] = v;
    }
    for (int idx = tid; idx < 48 * 12 * 9; idx += 256) {
      int oc = idx / 108, rem = idx - oc * 108;
      wS[idx] = c2w[(oc * 48 + icc * 12) * 9 + rem];
    }
    __syncthreads();
    for (int i = 0; i < 22; ++i) {
      int oidx = tid + i * 256;
      if (oidx >= 5472) break;
      int oc = oidx / 114, wp = oidx - oc * 114;
      int w0 = 2 * wp;
      float a0 = accA[i], a1 = accB[i];
      const float* wp9 = wS + oc * 108;
      for (int icl = 0; icl < 12; ++icl) {
#pragma unroll
        for (int a = 0; a < 3; ++a) {
          const float* xr = x1S + (icl * 3 + a) * 232 + w0;
          float x0 = xr[0], x1 = xr[1], x2 = xr[2], x3 = xr[3];
          float wA = wp9[icl * 9 + a * 3 + 0];
          float wB = wp9[icl * 9 + a * 3 + 1];
          float wC = wp9[icl * 9 + a * 3 + 2];
          a0 = fmaf(x0, wA, a0); a0 = fmaf(x1, wB, a0); a0 = fmaf(x2, wC, a0);
          a1 = fmaf(x1, wA, a1); a1 = fmaf(x2, wB, a1); a1 = fmaf(x3, wC, a1);
        }
      }
      accA[i] = a0; accB[i] = a1;
    }
  }
  for (int i = 0; i < 22; ++i) {
    int oidx = tid + i * 256;
    if (oidx >= 5472) break;
    int oc = oidx / 114, wp = oidx - oc * 114;
    float sc = bn2g[oc] * rsqrtf(bn2v[oc] + 1e-5f);
    float sh = bn2b[oc] - bn2m[oc] * sc;
    float v0 = fmaxf((accA[i] + c2b[oc]) * sc + sh, 0.f);
    float v1 = fmaxf((accB[i] + c2b[oc]) * sc + sh, 0.f);
    A[((bl * 48 + oc) * 512 + t) * 114 + wp] = fmaxf(v0, v1);
  }
}

// ---------------------------------------------------------------------------
// K2: conv3+bn3+relu+pool(1,2); GEMM-ready output. (unchanged)
// ---------------------------------------------------------------------------
__global__ __launch_bounds__(256) void conv3_kernel(
    const float* __restrict__ A,
    const float* __restrict__ c3w, const float* __restrict__ c3b,
    const float* __restrict__ bn3g, const float* __restrict__ bn3b,
    const float* __restrict__ bn3m, const float* __restrict__ bn3v,
    float* __restrict__ Bf)
{
  __shared__ float aS[16 * 3 * 116];
  __shared__ float wS[48 * 16 * 9];
  const int tid = threadIdx.x;
  const int bl = blockIdx.x / 510;
  const int t = blockIdx.x - bl * 510;

  for (int ocg = 0; ocg < 2; ++ocg) {
    float accA[11], accB[11];
#pragma unroll
    for (int i = 0; i < 11; ++i) { accA[i] = 0.f; accB[i] = 0.f; }
    for (int icc = 0; icc < 3; ++icc) {
      __syncthreads();
      for (int idx = tid; idx < 16 * 3 * 116; idx += 256) {
        int cl = idx / 348, rem = idx - cl * 348;
        int rr = rem / 116, cc = rem - rr * 116;
        int w = cc - 1;
        float v = 0.f;
        if (w >= 0 && w < 114) v = A[((bl * 48 + icc * 16 + cl) * 512 + t + rr) * 114 + w];
        aS[idx] = v;
      }
      for (int idx = tid; idx < 48 * 16 * 9; idx += 256) {
        int ocl = idx / 144, rem = idx - ocl * 144;
        wS[idx] = c3w[((ocg * 48 + ocl) * 48 + icc * 16) * 9 + rem];
      }
      __syncthreads();
      for (int i = 0; i < 11; ++i) {
        int oidx = tid + i * 256;
        if (oidx >= 2736) break;
        int ocl = oidx / 57, wp = oidx - ocl * 57;
        int w0 = 2 * wp;
        float a0 = accA[i], a1 = accB[i];
        const float* wb = wS + ocl * 144;
        for (int icl = 0; icl < 16; ++icl) {
#pragma unroll
          for (int a = 0; a < 3; ++a) {
            const float* xr = aS + (icl * 3 + a) * 116 + w0;
            float x0 = xr[0], x1 = xr[1], x2 = xr[2], x3 = xr[3];
            float wA = wb[icl * 9 + a * 3 + 0];
            float wB = wb[icl * 9 + a * 3 + 1];
            float wC = wb[icl * 9 + a * 3 + 2];
            a0 = fmaf(x0, wA, a0); a0 = fmaf(x1, wB, a0); a0 = fmaf(x2, wC, a0);
            a1 = fmaf(x1, wA, a1); a1 = fmaf(x2, wB, a1); a1 = fmaf(x3, wC, a1);
          }
        }
        accA[i] = a0; accB[i] = a1;
      }
    }
    for (int i = 0; i < 11; ++i) {
      int oidx = tid + i * 256;
      if (oidx >= 2736) break;
      int ocl = oidx / 57, wp = oidx - ocl * 57;
      int oc = ocg * 48 + ocl;
      float sc = bn3g[oc] * rsqrtf(bn3v[oc] + 1e-5f);
      float sh = bn3b[oc] - bn3m[oc] * sc;
      float v0 = fmaxf((accA[i] + c3b[oc]) * sc + sh, 0.f);
      float v1 = fmaxf((accB[i] + c3b[oc]) * sc + sh, 0.f);
      Bf[(size_t)(bl * 510 + t) * 5472 + oc * 57 + wp] = fmaxf(v0, v1);
    }
  }
}

// ---------------------------------------------------------------------------
// K3: fp32 NT GEMM  C = A * B^T + bias, output relaid to [t][16][768].
// ---------------------------------------------------------------------------
__global__ __launch_bounds__(256) void gemm_nt(
    const float* __restrict__ Am, const float* __restrict__ Bm,
    const float* __restrict__ bias, float* __restrict__ C,
    int M, int K, int lda, int ldb, int b0)
{
  __shared__ float As[64 * 33];
  __shared__ float Bs[64 * 33];
  const int tid = threadIdx.x;
  const int m0 = blockIdx.x * 64, n0 = blockIdx.y * 64;
  const int tx = tid & 15, ty = tid >> 4;
  const int kq = (tid & 7) * 4, rw = tid >> 3;
  float acc[4][4];
#pragma unroll
  for (int i = 0; i < 4; ++i)
#pragma unroll
    for (int j = 0; j < 4; ++j) acc[i][j] = 0.f;

  for (int k0 = 0; k0 < K; k0 += 32) {
    int m1 = m0 + rw, m2 = m1 + 32;
    float4 va = make_float4(0.f, 0.f, 0.f, 0.f), vb = va;
    if (m1 < M) va = *(const float4*)(Am + (size_t)m1 * lda + k0 + kq);
    if (m2 < M) vb = *(const float4*)(Am + (size_t)m2 * lda + k0 + kq);
    float4 wa = *(const float4*)(Bm + (size_t)(n0 + rw) * ldb + k0 + kq);
    float4 wb = *(const float4*)(Bm + (size_t)(n0 + rw + 32) * ldb + k0 + kq);
    As[rw * 33 + kq + 0] = va.x; As[rw * 33 + kq + 1] = va.y;
    As[rw * 33 + kq + 2] = va.z; As[rw * 33 + kq + 3] = va.w;
    As[(rw + 32) * 33 + kq + 0] = vb.x; As[(rw + 32) * 33 + kq + 1] = vb.y;
    As[(rw + 32) * 33 + kq + 2] = vb.z; As[(rw + 32) * 33 + kq + 3] = vb.w;
    Bs[rw * 33 + kq + 0] = wa.x; Bs[rw * 33 + kq + 1] = wa.y;
    Bs[rw * 33 + kq + 2] = wa.z; Bs[rw * 33 + kq + 3] = wa.w;
    Bs[(rw + 32) * 33 + kq + 0] = wb.x; Bs[(rw + 32) * 33 + kq + 1] = wb.y;
    Bs[(rw + 32) * 33 + kq + 2] = wb.z; Bs[(rw + 32) * 33 + kq + 3] = wb.w;
    __syncthreads();
#pragma unroll 8
    for (int k = 0; k < 32; ++k) {
      float av[4], bv[4];
#pragma unroll
      for (int i = 0; i < 4; ++i) av[i] = As[(ty * 4 + i) * 33 + k];
#pragma unroll
      for (int j = 0; j < 4; ++j) bv[j] = Bs[(tx * 4 + j) * 33 + k];
#pragma unroll
      for (int i = 0; i < 4; ++i)
#pragma unroll
        for (int j = 0; j < 4; ++j) acc[i][j] = fmaf(av[i], bv[j], acc[i][j]);
    }
    __syncthreads();
  }
#pragma unroll
  for (int i = 0; i < 4; ++i) {
    int m = m0 + ty * 4 + i;
    if (m >= M) continue;
    int bl2 = m / 510, tt2 = m - bl2 * 510;
    float* crow = C + ((size_t)tt2 * 16 + (b0 + bl2)) * 768;
#pragma unroll
    for (int j = 0; j < 4; ++j) {
      int n = n0 + tx * 4 + j;
      crow[n] = acc[i][j] + bias[n];
    }
  }
}

// ---------------------------------------------------------------------------
__global__ void init_state(ull* __restrict__ h1g, ull* __restrict__ h2g,
                           ull* __restrict__ prevg, unsigned* __restrict__ bar) {
  int gid = blockIdx.x * 256 + threadIdx.x;
  if (gid < 12288) { at_store(h1g + gid, 0ull); at_store(h2g + gid, 0ull); }
  if (gid < 2816) at_store(prevg + gid, 0ull);
  if (gid < BAR_U32)
    __hip_atomic_store(bar + gid, 0u, __ATOMIC_RELAXED, __HIP_MEMORY_SCOPE_AGENT);
}

// ---------------------------------------------------------------------------
// K6: persistent LSTM. 192 compute + 44 proj blocks; coherent gload_lds
// gathers; parallel flag waits with backoff; shfl publish; early-w2 schedule.
// ---------------------------------------------------------------------------
__global__ __launch_bounds__(256, 1) void lstm_kernel(
    const float* __restrict__ aco,   // [510][16][768]
    const float* __restrict__ whh0,  // [3072][768]
    const float* __restrict__ wih0,  // [3072][944]
    const float* __restrict__ wih1,  // [3072][768]
    const float* __restrict__ whh1,  // [3072][768]
    const float* __restrict__ bih0, const float* __restrict__ bhh0,
    const float* __restrict__ bih1, const float* __restrict__ bhh1,
    const float* __restrict__ pw,    // [440][768]
    const float* __restrict__ pb,
    const float* __restrict__ emb,   // [5][2]
    ull* __restrict__ h1g,           // [2][6144] chunked
    ull* __restrict__ h2g,           // [2][6144] chunked
    ull* __restrict__ prevg,         // [2][16][88]
    unsigned* __restrict__ bar,
    float* __restrict__ out)         // [16][510][440]
{
  __shared__ float bufA[16 * 772];   // x (compute) / h2 (proj)
  __shared__ float bufB[16 * 772];   // h1
  __shared__ float bufC[16 * 772];   // h2(t-1)
  __shared__ float prevs[16 * 176];  // [b][176]
  __shared__ float zl[16 * 17];
  __shared__ float zl2[16 * 17];
  __shared__ float embS[10];
  const int tid = threadIdx.x;
  const int s = tid & 15;
  const int r = tid >> 4;
  const int wv = tid >> 6;           // wave index
  const int ln = tid & 63;           // lane
  unsigned* f1 = bar + F1_OFF;
  unsigned* f2 = bar + F2_OFF;
  unsigned* fp = bar + FP_OFF;

  if (blockIdx.x < NCOMP) {
    // =======================================================================
    // COMPUTE BLOCK
    // =======================================================================
    const int uB = blockIdx.x * 4;
    const int j = (r >> 2) * 768 + uB + (r & 3);

    float wx[48], w0[48], w1[48], w2[48], wp[11];
    {
      const float* p = wih0 + (size_t)j * 944 + 48 * s;
#pragma unroll
      for (int i = 0; i < 48; i += 4) {
        float4 v = *(const float4*)(p + i);
        wx[i] = v.x; wx[i+1] = v.y; wx[i+2] = v.z; wx[i+3] = v.w;
      }
      p = whh0 + (size_t)j * 768 + 48 * s;
#pragma unroll
      for (int i = 0; i < 48; i += 4) {
        float4 v = *(const float4*)(p + i);
        w0[i] = v.x; w0[i+1] = v.y; w0[i+2] = v.z; w0[i+3] = v.w;
      }
      p = wih1 + (size_t)j * 768 + 48 * s;
#pragma unroll
      for (int i = 0; i < 48; i += 4) {
        float4 v = *(const float4*)(p + i);
        w1[i] = v.x; w1[i+1] = v.y; w1[i+2] = v.z; w1[i+3] = v.w;
      }
      p = whh1 + (size_t)j * 768 + 48 * s;
#pragma unroll
      for (int i = 0; i < 48; i += 4) {
        float4 v = *(const float4*)(p + i);
        w2[i] = v.x; w2[i+1] = v.y; w2[i+2] = v.z; w2[i+3] = v.w;
      }
      const float* pp = wih0 + (size_t)j * 944 + 768 + 11 * s;
#pragma unroll
      for (int i = 0; i < 11; ++i) wp[i] = pp[i];
    }
    float bl1[4], bl2[4], c1 = 0.f, c2 = 0.f;
    if (tid < 64) {
      int ul = tid >> 4;
#pragma unroll
      for (int g = 0; g < 4; ++g) {
        int jj = g * 768 + uB + ul;
        bl1[g] = bih0[jj] + bhh0[jj];
        bl2[g] = bih1[jj] + bhh1[jj];
      }
    }
    const int hdst = (blockIdx.x / 12) * 384 + (blockIdx.x % 12) * 2;

    // h1(-1) = 0, h2(-1) = 0
    for (int i = tid; i < 16 * 772; i += 256) { bufB[i] = 0.f; bufC[i] = 0.f; }

    // prologue: x(0) stage + dot
    float zxr[16];
    STAGE_X(0);
    __syncthreads();
#pragma unroll 4
    for (int b = 0; b < 16; ++b) {
      float p; CDOT48(wx, bufA + s * 772 + b * 48, p);
      zxr[b] = red16(p);
    }

    for (int t = 0; t < 510; ++t) {
      const int wbuf = t & 1, rbuf = wbuf ^ 1;
      __syncthreads();
      // ---- issue x(t+1) stage early; drains at the bufC barrier ----
      if (t < 509) STAGE_X(t + 1);
      // ---- w0 dot: bufB = h1(t-1) ----
#pragma unroll 4
      for (int b = 0; b < 16; ++b) {
        float p; CDOT48(w0, bufB + s * 772 + b * 48, p);
        p = red16(p);
        if (s == 0) zl[r * 17 + b] = zxr[b] + p;
      }
      // ---- direct f2 wait (h2(t-1) visible; ~1 step of slack) ----
      if (t) wait_flags_n(f2, (unsigned)t, tid, NCOMP);
      STAGE_H(h2g + rbuf * 6144, bufC);
      __syncthreads();   // drains bufC (+ x(t+1))
      // ---- EARLY w2 dot on bufC -> zl2 (covers the proj->prev chain) ----
#pragma unroll 4
      for (int b = 0; b < 16; ++b) {
        float p; CDOT48(w2, bufC + s * 772 + b * 48, p);
        p = red16(p);
        if (s == 0) zl2[r * 17 + b] = p;
      }
      // ---- prev(t-1) ready: all 44 proj flags >= t ----
      if (t) wait_flags_n(fp, (unsigned)t, tid, NPROJ);
      STAGE_PREV(rbuf);    // prevg zero-init covers t=0 (both parities)
      __syncthreads();
      // ---- prev dot ----
#pragma unroll 4
      for (int b = 0; b < 16; ++b) {
        const float* pvv = prevs + b * 176 + s * 11;
        float p = 0.f;
#pragma unroll
        for (int i = 0; i < 11; ++i) p = fmaf(wp[i], pvv[i], p);
        p = red16(p);
        if (s == 0) zl[r * 17 + b] += p;
      }
      __syncthreads();
      // ---- cell 1 + shfl publish (wave 0 only, program-ordered flag) ----
      if (tid < 64) {
        int ul = tid >> 4, bb = tid & 15;
        float zi = zl[(0 * 4 + ul) * 17 + bb] + bl1[0];
        float zf = zl[(1 * 4 + ul) * 17 + bb] + bl1[1];
        float zg = zl[(2 * 4 + ul) * 17 + bb] + bl1[2];
        float zo = zl[(3 * 4 + ul) * 17 + bb] + bl1[3];
        c1 = sigf(zf) * c1 + sigf(zi) * tanhf(zg);
        float h = sigf(zo) * tanhf(c1);
        int src1 = (tid >> 4) * 32 + (tid & 15);
        float v1 = __shfl(h, src1, 64);
        float v2 = __shfl(h, src1 + 16, 64);
        if (tid < 32) {
          int q = tid >> 4, bb2 = tid & 15;
          at_store(h1g + wbuf * 6144 + hdst + bb2 * 24 + q, pack2(v1, v2));
        }
        if (tid == 0) {
          __builtin_amdgcn_s_waitcnt(0);
          __atomic_signal_fence(__ATOMIC_SEQ_CST);
          __hip_atomic_store(f1 + blockIdx.x * 16, (unsigned)(t + 1),
                             __ATOMIC_RELAXED, __HIP_MEMORY_SCOPE_AGENT);
        }
      }
      // ---- wx dot for t+1 fills the f1-hide window (bufA fully staged) ----
      if (t < 509) {
#pragma unroll 4
        for (int b = 0; b < 16; ++b) {
          float p; CDOT48(wx, bufA + s * 772 + b * 48, p);
          zxr[b] = red16(p);
        }
      }
      // ---- f1 wait, stage h1(t), w1-only dot (+zl2 add) ----
      wait_flags_n(f1, (unsigned)(t + 1), tid, NCOMP);
      STAGE_H(h1g + wbuf * 6144, bufB);
      __syncthreads();
#pragma unroll 4
      for (int b = 0; b < 16; ++b) {
        float p; CDOT48(w1, bufB + s * 772 + b * 48, p);
        p = red16(p);
        if (s == 0) zl[r * 17 + b] = zl2[r * 17 + b] + p;
      }
      __syncthreads();
      // ---- cell 2 + shfl publish ----
      if (tid < 64) {
        int ul = tid >> 4, bb = tid & 15;
        float zi = zl[(0 * 4 + ul) * 17 + bb] + bl2[0];
        float zf = zl[(1 * 4 + ul) * 17 + bb] + bl2[1];
        float zg = zl[(2 * 4 + ul) * 17 + bb] + bl2[2];
        float zo = zl[(3 * 4 + ul) * 17 + bb] + bl2[3];
        c2 = sigf(zf) * c2 + sigf(zi) * tanhf(zg);
        float h = sigf(zo) * tanhf(c2);
        int src1 = (tid >> 4) * 32 + (tid & 15);
        float v1 = __shfl(h, src1, 64);
        float v2 = __shfl(h, src1 + 16, 64);
        if (tid < 32) {
          int q = tid >> 4, bb2 = tid & 15;
          at_store(h2g + wbuf * 6144 + hdst + bb2 * 24 + q, pack2(v1, v2));
        }
        if (tid == 0) {
          __builtin_amdgcn_s_waitcnt(0);
          __atomic_signal_fence(__ATOMIC_SEQ_CST);
          __hip_atomic_store(f2 + blockIdx.x * 16, (unsigned)(t + 1),
                             __ATOMIC_RELAXED, __HIP_MEMORY_SCOPE_AGENT);
        }
      }
    }
  } else {
    // =======================================================================
    // PROJECTION BLOCK: 10 logit rows (2 argmax groups), all 16 batches.
    // =======================================================================
    const int bp = blockIdx.x - NCOMP;   // 0..43
    const int prow = bp * 10 + r;        // valid for r < 10
    float pwr[48];
    float pbv = 0.f;
    if (r < 10) {
      const float* p = pw + (size_t)prow * 768 + 48 * s;
#pragma unroll
      for (int i = 0; i < 48; i += 4) {
        float4 v = *(const float4*)(p + i);
        pwr[i] = v.x; pwr[i+1] = v.y; pwr[i+2] = v.z; pwr[i+3] = v.w;
      }
      pbv = pb[prow];
    } else {
#pragma unroll
      for (int i = 0; i < 48; ++i) pwr[i] = 0.f;
    }
    if (tid < 10) embS[tid] = emb[tid];
    __syncthreads();

    for (int t = 0; t < 510; ++t) {
      const int wbuf = t & 1;
      wait_flags_n(f2, (unsigned)(t + 1), tid, NCOMP);
      STAGE_H(h2g + wbuf * 6144, bufA);
      __syncthreads();
#pragma unroll 4
      for (int b = 0; b < 16; ++b) {
        float p; CDOT48(pwr, bufA + s * 772 + b * 48, p);
        p = red16(p);
        if (r < 10 && s == 0) {
          float lg = p + pbv;
          out[((size_t)b * 510 + t) * 440 + prow] = lg;
          zl[r * 17 + b] = lg;
        }
      }
      __syncthreads();
      if (tid < 32) {
        int q = tid >> 4, bb = tid & 15;
        float best = zl[(q * 5) * 17 + bb]; int bi = 0;
#pragma unroll
        for (int c = 1; c < 5; ++c) {
          float v = zl[(q * 5 + c) * 17 + bb];
          if (v > best) { best = v; bi = c; }
        }
        at_store(prevg + wbuf * 1408 + bb * 88 + bp * 2 + q,
                 pack2(embS[bi * 2], embS[bi * 2 + 1]));
      }
      if (tid == 0) {
        __builtin_amdgcn_s_waitcnt(0);
        __atomic_signal_fence(__ATOMIC_SEQ_CST);
        __hip_atomic_store(fp + bp * 16, (unsigned)(t + 1),
                           __ATOMIC_RELAXED, __HIP_MEMORY_SCOPE_AGENT);
      }
    }
  }
}

// ---------------------------------------------------------------------------
extern "C" void kernel_launch(void* const* d_in, const int* in_sizes, int n_in,
                              void* d_out, int out_size, void* d_ws, size_t ws_size,
                              hipStream_t stream) {
  (void)in_sizes; (void)n_in; (void)out_size;
  const float* mel  = (const float*)d_in[0];
  const float* c1w  = (const float*)d_in[1];
  const float* c1b  = (const float*)d_in[2];
  const float* c2w  = (const float*)d_in[3];
  const float* c2b  = (const float*)d_in[4];
  const float* c3w  = (const float*)d_in[5];
  const float* c3b  = (const float*)d_in[6];
  const float* bn1g = (const float*)d_in[7];
  const float* bn1b = (const float*)d_in[8];
  const float* bn1m = (const float*)d_in[9];
  const float* bn1v = (const float*)d_in[10];
  const float* bn2g = (const float*)d_in[11];
  const float* bn2b = (const float*)d_in[12];
  const float* bn2m = (const float*)d_in[13];
  const float* bn2v = (const float*)d_in[14];
  const float* bn3g = (const float*)d_in[15];
  const float* bn3b = (const float*)d_in[16];
  const float* bn3m = (const float*)d_in[17];
  const float* bn3v = (const float*)d_in[18];
  const float* fcw  = (const float*)d_in[19];
  const float* fcb  = (const float*)d_in[20];
  const float* wih0 = (const float*)d_in[21];
  const float* whh0 = (const float*)d_in[22];
  const float* bih0 = (const float*)d_in[23];
  const float* bhh0 = (const float*)d_in[24];
  const float* wih1 = (const float*)d_in[25];
  const float* whh1 = (const float*)d_in[26];
  const float* bih1 = (const float*)d_in[27];
  const float* bhh1 = (const float*)d_in[28];
  const float* pw   = (const float*)d_in[29];
  const float* pb   = (const float*)d_in[30];
  const float* emb  = (const float*)d_in[31];

  float* ws = (float*)d_ws;
  float* outp = (float*)d_out;

  const size_t ST_ULL = 12288ull + 12288ull + 2816ull;
  int CB = 1;
  for (int cb = 4; cb >= 1; cb >>= 1) {
    size_t need = (ACO_FL + (size_t)cb * 48 * 512 * 114 + (size_t)cb * 510 * 5472) * 4
                + ST_ULL * 8 + BAR_U32 * 4 + 1024;
    if (ws_size >= need) { CB = cb; break; }
  }
  const int nchunks = 16 / CB;
  const size_t A_FL  = (size_t)CB * 48 * 512 * 114;
  const size_t BF_FL = (size_t)CB * 510 * 5472;

  float* aco = ws;                       // [510][16][768]
  float* Ac  = ws + ACO_FL;
  float* Bfc = Ac + A_FL;
  ull* h1g   = (ull*)(Bfc + BF_FL);
  ull* h2g   = h1g + 12288;
  ull* prevg = h2g + 12288;
  unsigned* bar = (unsigned*)(prevg + 2816);

  for (int ch = 0; ch < nchunks; ++ch) {
    int b0 = ch * CB;
    hipLaunchKernelGGL(conv12_kernel, dim3(CB * 512), dim3(256), 0, stream,
                       mel, c1w, c1b, bn1g, bn1b, bn1m, bn1v,
                       c2w, c2b, bn2g, bn2b, bn2m, bn2v, Ac, b0);
    hipLaunchKernelGGL(conv3_kernel, dim3(CB * 510), dim3(256), 0, stream,
                       Ac, c3w, c3b, bn3g, bn3b, bn3m, bn3v, Bfc);
    int M = CB * 510;
    hipLaunchKernelGGL(gemm_nt, dim3((M + 63) / 64, 12), dim3(256), 0, stream,
                       Bfc, fcw, fcb, aco, M, 5472, 5472, 5472, b0);
  }
  hipLaunchKernelGGL(init_state, dim3(48), dim3(256), 0, stream,
                     h1g, h2g, prevg, bar);

  {
    void* args[] = {
      (void*)&aco, (void*)&whh0, (void*)&wih0, (void*)&wih1, (void*)&whh1,
      (void*)&bih0, (void*)&bhh0, (void*)&bih1, (void*)&bhh1,
      (void*)&pw, (void*)&pb, (void*)&emb,
      (void*)&h1g, (void*)&h2g, (void*)&prevg, (void*)&bar, (void*)&outp
    };
    hipError_t e = hipLaunchCooperativeKernel((const void*)lstm_kernel,
                                              dim3(NCOMP + NPROJ), dim3(256),
                                              args, 0, stream);
    if (e != hipSuccess) {
      (void)hipGetLastError();
      hipLaunchKernelGGL(lstm_kernel, dim3(NCOMP + NPROJ), dim3(256), 0, stream,
                         aco, whh0, wih0, wih1, whh1, bih0, bhh0, bih1, bhh1,
                         pw, pb, emb, h1g, h2g, prevg, bar, outp);
    }
  }
}